// Round 12
// baseline (149.850 us; speedup 1.0000x reference)
//
#include <hip/hip_runtime.h>
#include <hip/hip_bf16.h>
#include <math.h>

#define NB 2
#define NS 2048
#define ND 768
#define NH 12
#define HD 64
#define WIN 128
#define N_QKV 2304
#define QKN (NB * NH * NS * HD)   // 3145728

typedef __attribute__((ext_vector_type(8))) short short8;
typedef __attribute__((ext_vector_type(4))) short short4v;
typedef __attribute__((ext_vector_type(4))) float float4v;

static __device__ __forceinline__ short f2bf(float f) {
  __hip_bfloat16 h = __float2bfloat16(f);
  short s;
  __builtin_memcpy(&s, &h, 2);
  return s;
}

static __device__ __forceinline__ int pack_bf2(float a, float b) {
  return (int)(unsigned short)f2bf(a) | ((int)(unsigned short)f2bf(b) << 16);
}

static __device__ __forceinline__ void async_copy16(void* lds, const void* g) {
  __builtin_amdgcn_global_load_lds(
      (const __attribute__((address_space(1))) unsigned int*)g,
      (__attribute__((address_space(3))) unsigned int*)(unsigned int)(unsigned long long)lds,
      16, 0, 0);
}

// ---------------------------------------------------------------------------
// Merged prep kernel: x cvt (3072 units) + Wqkv^T (1728) + Wout^T (576).
// ---------------------------------------------------------------------------
__global__ __launch_bounds__(256) void prep_kernel(
    const float* __restrict__ x, const float* __restrict__ Wqkv,
    const float* __restrict__ Wout, short* __restrict__ xb,
    short* __restrict__ Wqkvt, short* __restrict__ Woutt)
{
  __shared__ float t[32][33];
  const int u = blockIdx.x;
  const int tid = threadIdx.x;

  if (u < 3072) {
    const int i = u * 1024 + tid * 4;
    const float4 v = *(const float4*)(x + i);
    short4v o;
    o[0] = f2bf(v.x); o[1] = f2bf(v.y); o[2] = f2bf(v.z); o[3] = f2bf(v.w);
    *(short4v*)(xb + i) = o;
    return;
  }

  const bool isqkv = (u < 4800);
  const float* in = isqkv ? Wqkv : Wout;
  short* out = isqkv ? Wqkvt : Woutt;
  const int C = isqkv ? N_QKV : ND;       // in cols
  const int tt = u - (isqkv ? 3072 : 4800);
  const int nbx = C / 32;
  const int bx = (tt % nbx) * 32;         // col base
  const int by = (tt / nbx) * 32;         // row base
  const int tx = tid & 31, ty = tid >> 5; // ty 0..7
#pragma unroll
  for (int i = 0; i < 32; i += 8)
    t[ty + i][tx] = in[(size_t)(by + ty + i) * C + bx + tx];
  __syncthreads();
#pragma unroll
  for (int i = 0; i < 32; i += 8)
    out[(size_t)(bx + ty + i) * ND + by + tx] = f2bf(t[tx][ty + i]);
}

// ---------------------------------------------------------------------------
// MFMA GEMM: 128x64 tile, BK=64, 4 waves each 32x64 via 2x4 16x16x32 bf16
// frags, global_load_lds width-16 staging, XOR-swizzled K-chunk LDS slots.
// XCD-aware tile swizzle (R10, +3.5us). MODE 0: qkv bias+RoPE epilogue;
// MODE 1: plain fp32 out+bias. Intrinsics only (libm scratch trap, R4).
// ---------------------------------------------------------------------------
template <int MODE>
__global__ __launch_bounds__(256) void mfma_gemm128_kernel(
    const short* __restrict__ A, const short* __restrict__ Bt,
    const float* __restrict__ bias, const int* __restrict__ layer_idx_p,
    short* __restrict__ Qb, short* __restrict__ Kb, short* __restrict__ VT,
    float* __restrict__ Out, int K, int Ncols, int nTN, int mPerXcd)
{
  __shared__ short As[128 * 64];   // 16 KB
  __shared__ short Bs[64 * 64];    //  8 KB
  const int tid = threadIdx.x;
  const int w = tid >> 6, lane = tid & 63;
  const int c = lane & 15, g = lane >> 4;

  const int id = blockIdx.x;
  const int xcd = id & 7;
  const int k = id >> 3;
  const int mt = xcd * mPerXcd + k / nTN;
  const int nt = k - (k / nTN) * nTN;
  const int bm = mt * 128, bn = nt * 64;

  const int lr = lane >> 3;            // staging row 0..7
  const int gch = (lane & 7) ^ lr;     // swizzled global K-chunk index

  float4v acc[2][4];
#pragma unroll
  for (int i = 0; i < 2; ++i)
#pragma unroll
    for (int j = 0; j < 4; ++j) acc[i][j] = (float4v){0.f, 0.f, 0.f, 0.f};

  const short* Ag = A + (size_t)(bm + w * 32 + lr) * K + gch * 8;
  const short* Bg = Bt + (size_t)(bn + w * 16 + lr) * K + gch * 8;
  short* AsW = As + (w * 32) * 64;     // wave-uniform LDS stage base
  short* BsW = Bs + (w * 16) * 64;

  const int cl7 = c & 7;
  const short* aw = As + (w * 32 + c) * 64;
  const short* bwp = Bs + c * 64;

  for (int k0 = 0; k0 < K; k0 += 64) {
    async_copy16(AsW,        Ag + k0);
    async_copy16(AsW + 512,  Ag + k0 + (size_t)8 * K);
    async_copy16(AsW + 1024, Ag + k0 + (size_t)16 * K);
    async_copy16(AsW + 1536, Ag + k0 + (size_t)24 * K);
    async_copy16(BsW,        Bg + k0);
    async_copy16(BsW + 512,  Bg + k0 + (size_t)8 * K);
    __syncthreads();   // drains vmcnt -> staged data visible

    short8 af[2][2], bfr[4][2];
#pragma unroll
    for (int t = 0; t < 2; ++t) {
      const int slot = ((t * 4 + g) ^ cl7) * 8;
#pragma unroll
      for (int i = 0; i < 2; ++i) af[i][t] = *(const short8*)(aw + i * 16 * 64 + slot);
#pragma unroll
      for (int j = 0; j < 4; ++j) bfr[j][t] = *(const short8*)(bwp + j * 16 * 64 + slot);
    }
#pragma unroll
    for (int t = 0; t < 2; ++t)
#pragma unroll
      for (int i = 0; i < 2; ++i)
#pragma unroll
        for (int j = 0; j < 4; ++j)
          acc[i][j] = __builtin_amdgcn_mfma_f32_16x16x32_bf16(af[i][t], bfr[j][t], acc[i][j], 0, 0, 0);
    __syncthreads();   // protect LDS before next stage
  }

  const int wm = bm + w * 32;
  const int wn = bn;
  float bj[4];
#pragma unroll
  for (int j = 0; j < 4; ++j) bj[j] = bias[wn + j * 16 + c];

  if (MODE == 1) {
#pragma unroll
    for (int i = 0; i < 2; ++i)
#pragma unroll
      for (int j = 0; j < 4; ++j)
#pragma unroll
        for (int r = 0; r < 4; ++r)
          Out[(size_t)(wm + i * 16 + 4 * g + r) * Ncols + wn + j * 16 + c] =
              acc[i][j][r] + bj[j];
  } else {
    const int which = bn / ND;               // uniform per block (768%64==0)
    const int hd0 = wn - which * ND;         // 64-aligned
    const int h = hd0 >> 6;
    const int bidx = bm >> 11;
    const int srow = (bm & (NS - 1)) + w * 32;

    if (which == 2) {
      // V: no RoPE; VT[bh][d][s], short4 along s
#pragma unroll
      for (int j = 0; j < 4; ++j) {
        const int d = j * 16 + c;
        short* vbase = VT + ((size_t)(bidx * NH + h) * HD + d) * NS;
#pragma unroll
        for (int i = 0; i < 2; ++i) {
          short4v v4;
#pragma unroll
          for (int r = 0; r < 4; ++r) v4[r] = f2bf(acc[i][j][r] + bj[j]);
          *(short4v*)(vbase + srow + i * 16 + 4 * g) = v4;
        }
      }
    } else {
      const bool is_global = ((*layer_idx_p) % 3) == 0;
      const float theta = is_global ? 160000.0f : 10000.0f;
      const float nlt = -__logf(theta) * (1.0f / 64.0f);
      short* dst = which ? Kb : Qb;
      const bool oddc = (c & 1);
#pragma unroll
      for (int j = 0; j < 4; ++j) {
        const int d = j * 16 + c;
        const float freq = __expf((float)(d & ~1) * nlt);
#pragma unroll
        for (int i = 0; i < 2; ++i) {
#pragma unroll
          for (int r = 0; r < 4; ++r) {
            const float val = acc[i][j][r] + bj[j];
            const float partner = __shfl_xor(val, 1);
            const int s = srow + i * 16 + 4 * g + r;
            float sn, cs;
            __sincosf((float)s * freq, &sn, &cs);
            const float o = oddc ? (val * cs + partner * sn)
                                 : (val * cs - partner * sn);
            dst[((size_t)(bidx * NH + h) * NS + s) * HD + d] = f2bf(o);
          }
        }
      }
    }
  }
}

// ---------------------------------------------------------------------------
// MFMA banded flash attention (fixed-reference softmax, R7; XCD swizzle,
// R10). R11: (a) wave-uniform FAST path — 7 of 9 tiles are fully valid
// (kt in [q0-113, q0+97] and in-bounds) and skip all mask VALU;
// (b) P-transpose via 4 packed-bf16x2 b32 + 8 ds_bpermute + 4 selects
// (was 16 __shfl) — halves DS ops on the QK->PV chain. Bit-identical.
// ---------------------------------------------------------------------------
__global__ __launch_bounds__(256) void attn_mfma_kernel(
    const short* __restrict__ Qb, const short* __restrict__ Kb,
    const short* __restrict__ VT, short* __restrict__ CTXb,
    const int* __restrict__ layer_idx_p)
{
  const int lane = threadIdx.x & 63;
  const int wv = threadIdx.x >> 6;
  const int c = lane & 15;
  const int g = lane >> 4;

  // swizzle: xcd = id&7 owns bh in [xcd*3, xcd*3+3)
  const int id = blockIdx.x;
  const int xcd = id & 7;
  const int k = id >> 3;               // 0..95
  const int bh = xcd * 3 + (k >> 5);
  const int qt = k & 31;

  const int b = bh / NH;
  const int h = bh - b * NH;
  const int q0 = qt * 64 + wv * 16;
  const bool is_global = ((*layer_idx_p) % 3) == 0;
  const size_t base = (size_t)bh * NS * HD;

  const short* qrow = Qb + base + (size_t)(q0 + c) * HD + g * 8;
  const short8 qf0 = *(const short8*)(qrow);
  const short8 qf1 = *(const short8*)(qrow + 32);

  float4v O0 = {0.f, 0.f, 0.f, 0.f}, O1 = O0, O2 = O0, O3 = O0;
  float lacc = 0.0f;
  const int q = q0 + c;

  const int lo = is_global ? 0 : q0 - 128;
  const int hi = is_global ? (NS - 1) : q0 + 143;

  const int srcA = (2 * (g & 1)) * 16 + c;
  const int aA = srcA * 4;
  const int aB = (srcA + 16) * 4;

  for (int kt = lo; kt <= hi; kt += 32) {
    if (kt + 31 < 0 || kt >= NS) continue;
    // fully-valid tile for ALL 16 queries & 32 keys? (wave-uniform)
    const bool fast = (kt >= 0) & (kt + 32 <= NS) &
                      (is_global | ((kt >= q0 - 113) & (kt <= q0 + 97)));

    const int k1c = min(max(kt + c, 0), NS - 1);
    const int k2c = min(max(kt + 16 + c, 0), NS - 1);
    const short* kr1 = Kb + base + (size_t)k1c * HD + g * 8;
    const short* kr2 = Kb + base + (size_t)k2c * HD + g * 8;
    const short8 kf10 = *(const short8*)kr1;
    const short8 kf11 = *(const short8*)(kr1 + 32);
    const short8 kf20 = *(const short8*)kr2;
    const short8 kf21 = *(const short8*)(kr2 + 32);
    float4v st1 = {0.f, 0.f, 0.f, 0.f}, st2 = {0.f, 0.f, 0.f, 0.f};
    st1 = __builtin_amdgcn_mfma_f32_16x16x32_bf16(kf10, qf0, st1, 0, 0, 0);
    st1 = __builtin_amdgcn_mfma_f32_16x16x32_bf16(kf11, qf1, st1, 0, 0, 0);
    st2 = __builtin_amdgcn_mfma_f32_16x16x32_bf16(kf20, qf0, st2, 0, 0, 0);
    st2 = __builtin_amdgcn_mfma_f32_16x16x32_bf16(kf21, qf1, st2, 0, 0, 0);

    float p1[4], p2[4];
    if (fast) {
#pragma unroll
      for (int r = 0; r < 4; ++r) {
        p1[r] = __expf(st1[r] * 0.125f);
        p2[r] = __expf(st2[r] * 0.125f);
        lacc += p1[r] + p2[r];
      }
    } else {
#pragma unroll
      for (int r = 0; r < 4; ++r) {
        const int key1 = kt + 4 * g + r;
        const int key2 = key1 + 16;
        const bool v1 = (key1 >= 0) & (key1 < NS) &
                        (is_global | ((key1 - q <= WIN) & (q - key1 <= WIN)));
        const bool v2 = (key2 >= 0) & (key2 < NS) &
                        (is_global | ((key2 - q <= WIN) & (q - key2 <= WIN)));
        p1[r] = __expf(v1 ? st1[r] * 0.125f : -1e30f);
        p2[r] = __expf(v2 ? st2[r] * 0.125f : -1e30f);
        lacc += p1[r] + p2[r];
      }
    }

    // P^T -> B-frag via packed bpermute: pf[j] = P[key=8g+j][q=c]
    const int A1 = pack_bf2(p1[0], p1[1]), B1 = pack_bf2(p1[2], p1[3]);
    const int A2 = pack_bf2(p2[0], p2[1]), B2 = pack_bf2(p2[2], p2[3]);
    const int loA1 = __builtin_amdgcn_ds_bpermute(aA, A1);
    const int loA2 = __builtin_amdgcn_ds_bpermute(aA, A2);
    const int hiA1 = __builtin_amdgcn_ds_bpermute(aA, B1);
    const int hiA2 = __builtin_amdgcn_ds_bpermute(aA, B2);
    const int loB1 = __builtin_amdgcn_ds_bpermute(aB, A1);
    const int loB2 = __builtin_amdgcn_ds_bpermute(aB, A2);
    const int hiB1 = __builtin_amdgcn_ds_bpermute(aB, B1);
    const int hiB2 = __builtin_amdgcn_ds_bpermute(aB, B2);
    union { int i[4]; short8 s; } u;
    u.i[0] = (g < 2) ? loA1 : loA2;   // pf[0..1] = keys 8g+0,1
    u.i[1] = (g < 2) ? hiA1 : hiA2;   // pf[2..3]
    u.i[2] = (g < 2) ? loB1 : loB2;   // pf[4..5]
    u.i[3] = (g < 2) ? hiB1 : hiB2;   // pf[6..7]
    const short8 pf = u.s;

    const int ks = min(max(kt + 8 * g, 0), NS - 8);
    const short* vrow = VT + base + (size_t)c * NS + ks;
    const short8 vf0 = *(const short8*)(vrow);
    const short8 vf1 = *(const short8*)(vrow + 16 * NS);
    const short8 vf2 = *(const short8*)(vrow + 32 * NS);
    const short8 vf3 = *(const short8*)(vrow + 48 * NS);
    O0 = __builtin_amdgcn_mfma_f32_16x16x32_bf16(vf0, pf, O0, 0, 0, 0);
    O1 = __builtin_amdgcn_mfma_f32_16x16x32_bf16(vf1, pf, O1, 0, 0, 0);
    O2 = __builtin_amdgcn_mfma_f32_16x16x32_bf16(vf2, pf, O2, 0, 0, 0);
    O3 = __builtin_amdgcn_mfma_f32_16x16x32_bf16(vf3, pf, O3, 0, 0, 0);
  }

  // epilogue: one cross-quad reduction of l, then scale+store
  lacc += __shfl_xor(lacc, 16);
  lacc += __shfl_xor(lacc, 32);
  const float inv = 1.0f / lacc;
  short* crow = CTXb + ((size_t)(b * NS + q) * NH + h) * HD;
#pragma unroll
  for (int r = 0; r < 4; ++r) {
    const int d = 4 * g + r;
    crow[d]      = f2bf(O0[r] * inv);
    crow[d + 16] = f2bf(O1[r] * inv);
    crow[d + 32] = f2bf(O2[r] * inv);
    crow[d + 48] = f2bf(O3[r] * inv);
  }
}

// ---------------------------------------------------------------------------
extern "C" void kernel_launch(void* const* d_in, const int* in_sizes, int n_in,
                              void* d_out, int out_size, void* d_ws, size_t ws_size,
                              hipStream_t stream) {
  const float* x    = (const float*)d_in[0];
  const float* Wqkv = (const float*)d_in[1];
  const float* bqkv = (const float*)d_in[2];
  const float* Wout = (const float*)d_in[3];
  const float* bout = (const float*)d_in[4];
  const int* layer_idx = (const int*)d_in[5];

  short* xb    = (short*)d_ws;                         // [4096][768]
  short* Wqkvt = xb + (size_t)NB * NS * ND;            // [2304][768]
  short* Woutt = Wqkvt + (size_t)ND * N_QKV;           // [768][768]
  short* Qb    = Woutt + (size_t)ND * ND;              // [bh][s][64]
  short* Kb    = Qb + (size_t)QKN;
  short* VT    = Kb + (size_t)QKN;                     // [bh][64][s]
  short* CTXb  = VT + (size_t)QKN;                     // [4096][768]
  // total: 18087936 shorts = 36.2 MB

  // phase 0: all preps in one dispatch
  prep_kernel<<<5376, 256, 0, stream>>>(x, Wqkv, Wout, xb, Wqkvt, Woutt);

  // QKV GEMM + RoPE: M=4096, N=2304, K=768. 32 m-tiles x 36 n-tiles = 1152.
  mfma_gemm128_kernel<0><<<1152, 256, 0, stream>>>(
      xb, Wqkvt, bqkv, layer_idx, Qb, Kb, VT, nullptr, ND, N_QKV, 36, 4);

  attn_mfma_kernel<<<NB * NH * (NS / 64), 256, 0, stream>>>(Qb, Kb, VT, CTXb, layer_idx);

  // Out projection: M=4096, N=768, K=768. 32 m-tiles x 12 n-tiles = 384.
  mfma_gemm128_kernel<1><<<384, 256, 0, stream>>>(
      CTXb, Woutt, bout, layer_idx, nullptr, nullptr, nullptr, (float*)d_out, ND, ND, 12, 4);
}

// Round 13
// 148.085 us; speedup vs baseline: 1.0119x; 1.0119x over previous
//
#include <hip/hip_runtime.h>
#include <hip/hip_bf16.h>
#include <math.h>

#define NB 2
#define NS 2048
#define ND 768
#define NH 12
#define HD 64
#define WIN 128
#define N_QKV 2304
#define QKN (NB * NH * NS * HD)   // 3145728

typedef __attribute__((ext_vector_type(8))) short short8;
typedef __attribute__((ext_vector_type(4))) short short4v;
typedef __attribute__((ext_vector_type(4))) float float4v;

static __device__ __forceinline__ short f2bf(float f) {
  __hip_bfloat16 h = __float2bfloat16(f);
  short s;
  __builtin_memcpy(&s, &h, 2);
  return s;
}

static __device__ __forceinline__ void async_copy16(void* lds, const void* g) {
  __builtin_amdgcn_global_load_lds(
      (const __attribute__((address_space(1))) unsigned int*)g,
      (__attribute__((address_space(3))) unsigned int*)(unsigned int)(unsigned long long)lds,
      16, 0, 0);
}

// ---------------------------------------------------------------------------
// Merged prep kernel: x cvt (3072 units) + Wqkv^T (1728) + Wout^T (576).
// ---------------------------------------------------------------------------
__global__ __launch_bounds__(256) void prep_kernel(
    const float* __restrict__ x, const float* __restrict__ Wqkv,
    const float* __restrict__ Wout, short* __restrict__ xb,
    short* __restrict__ Wqkvt, short* __restrict__ Woutt)
{
  __shared__ float t[32][33];
  const int u = blockIdx.x;
  const int tid = threadIdx.x;

  if (u < 3072) {
    const int i = u * 1024 + tid * 4;
    const float4 v = *(const float4*)(x + i);
    short4v o;
    o[0] = f2bf(v.x); o[1] = f2bf(v.y); o[2] = f2bf(v.z); o[3] = f2bf(v.w);
    *(short4v*)(xb + i) = o;
    return;
  }

  const bool isqkv = (u < 4800);
  const float* in = isqkv ? Wqkv : Wout;
  short* out = isqkv ? Wqkvt : Woutt;
  const int C = isqkv ? N_QKV : ND;       // in cols
  const int tt = u - (isqkv ? 3072 : 4800);
  const int nbx = C / 32;
  const int bx = (tt % nbx) * 32;         // col base
  const int by = (tt / nbx) * 32;         // row base
  const int tx = tid & 31, ty = tid >> 5; // ty 0..7
#pragma unroll
  for (int i = 0; i < 32; i += 8)
    t[ty + i][tx] = in[(size_t)(by + ty + i) * C + bx + tx];
  __syncthreads();
#pragma unroll
  for (int i = 0; i < 32; i += 8)
    out[(size_t)(bx + ty + i) * ND + by + tx] = f2bf(t[tx][ty + i]);
}

// ---------------------------------------------------------------------------
// MFMA GEMM: 128x64 tile, BK=64, 4 waves each 32x64 via 2x4 16x16x32 bf16
// frags, global_load_lds width-16 staging, XOR-swizzled K-chunk LDS slots.
// XCD-aware tile swizzle (R10, +3.5us). MODE 0: qkv bias+RoPE epilogue;
// MODE 1: plain fp32 out+bias. Intrinsics only (libm scratch trap, R4).
// ---------------------------------------------------------------------------
template <int MODE>
__global__ __launch_bounds__(256) void mfma_gemm128_kernel(
    const short* __restrict__ A, const short* __restrict__ Bt,
    const float* __restrict__ bias, const int* __restrict__ layer_idx_p,
    short* __restrict__ Qb, short* __restrict__ Kb, short* __restrict__ VT,
    float* __restrict__ Out, int K, int Ncols, int nTN, int mPerXcd)
{
  __shared__ short As[128 * 64];   // 16 KB
  __shared__ short Bs[64 * 64];    //  8 KB
  const int tid = threadIdx.x;
  const int w = tid >> 6, lane = tid & 63;
  const int c = lane & 15, g = lane >> 4;

  const int id = blockIdx.x;
  const int xcd = id & 7;
  const int k = id >> 3;
  const int mt = xcd * mPerXcd + k / nTN;
  const int nt = k - (k / nTN) * nTN;
  const int bm = mt * 128, bn = nt * 64;

  const int lr = lane >> 3;            // staging row 0..7
  const int gch = (lane & 7) ^ lr;     // swizzled global K-chunk index

  float4v acc[2][4];
#pragma unroll
  for (int i = 0; i < 2; ++i)
#pragma unroll
    for (int j = 0; j < 4; ++j) acc[i][j] = (float4v){0.f, 0.f, 0.f, 0.f};

  const short* Ag = A + (size_t)(bm + w * 32 + lr) * K + gch * 8;
  const short* Bg = Bt + (size_t)(bn + w * 16 + lr) * K + gch * 8;
  short* AsW = As + (w * 32) * 64;     // wave-uniform LDS stage base
  short* BsW = Bs + (w * 16) * 64;

  const int cl7 = c & 7;
  const short* aw = As + (w * 32 + c) * 64;
  const short* bwp = Bs + c * 64;

  for (int k0 = 0; k0 < K; k0 += 64) {
    async_copy16(AsW,        Ag + k0);
    async_copy16(AsW + 512,  Ag + k0 + (size_t)8 * K);
    async_copy16(AsW + 1024, Ag + k0 + (size_t)16 * K);
    async_copy16(AsW + 1536, Ag + k0 + (size_t)24 * K);
    async_copy16(BsW,        Bg + k0);
    async_copy16(BsW + 512,  Bg + k0 + (size_t)8 * K);
    __syncthreads();   // drains vmcnt -> staged data visible

    short8 af[2][2], bfr[4][2];
#pragma unroll
    for (int t = 0; t < 2; ++t) {
      const int slot = ((t * 4 + g) ^ cl7) * 8;
#pragma unroll
      for (int i = 0; i < 2; ++i) af[i][t] = *(const short8*)(aw + i * 16 * 64 + slot);
#pragma unroll
      for (int j = 0; j < 4; ++j) bfr[j][t] = *(const short8*)(bwp + j * 16 * 64 + slot);
    }
#pragma unroll
    for (int t = 0; t < 2; ++t)
#pragma unroll
      for (int i = 0; i < 2; ++i)
#pragma unroll
        for (int j = 0; j < 4; ++j)
          acc[i][j] = __builtin_amdgcn_mfma_f32_16x16x32_bf16(af[i][t], bfr[j][t], acc[i][j], 0, 0, 0);
    __syncthreads();   // protect LDS before next stage
  }

  const int wm = bm + w * 32;
  const int wn = bn;
  float bj[4];
#pragma unroll
  for (int j = 0; j < 4; ++j) bj[j] = bias[wn + j * 16 + c];

  if (MODE == 1) {
#pragma unroll
    for (int i = 0; i < 2; ++i)
#pragma unroll
      for (int j = 0; j < 4; ++j)
#pragma unroll
        for (int r = 0; r < 4; ++r)
          Out[(size_t)(wm + i * 16 + 4 * g + r) * Ncols + wn + j * 16 + c] =
              acc[i][j][r] + bj[j];
  } else {
    const int which = bn / ND;               // uniform per block (768%64==0)
    const int hd0 = wn - which * ND;         // 64-aligned
    const int h = hd0 >> 6;
    const int bidx = bm >> 11;
    const int srow = (bm & (NS - 1)) + w * 32;

    if (which == 2) {
      // V: no RoPE; VT[bh][d][s], short4 along s
#pragma unroll
      for (int j = 0; j < 4; ++j) {
        const int d = j * 16 + c;
        short* vbase = VT + ((size_t)(bidx * NH + h) * HD + d) * NS;
#pragma unroll
        for (int i = 0; i < 2; ++i) {
          short4v v4;
#pragma unroll
          for (int r = 0; r < 4; ++r) v4[r] = f2bf(acc[i][j][r] + bj[j]);
          *(short4v*)(vbase + srow + i * 16 + 4 * g) = v4;
        }
      }
    } else {
      const bool is_global = ((*layer_idx_p) % 3) == 0;
      const float theta = is_global ? 160000.0f : 10000.0f;
      const float nlt = -__logf(theta) * (1.0f / 64.0f);
      short* dst = which ? Kb : Qb;
      const bool oddc = (c & 1);
#pragma unroll
      for (int j = 0; j < 4; ++j) {
        const int d = j * 16 + c;
        const float freq = __expf((float)(d & ~1) * nlt);
#pragma unroll
        for (int i = 0; i < 2; ++i) {
#pragma unroll
          for (int r = 0; r < 4; ++r) {
            const float val = acc[i][j][r] + bj[j];
            const float partner = __shfl_xor(val, 1);
            const int s = srow + i * 16 + 4 * g + r;
            float sn, cs;
            __sincosf((float)s * freq, &sn, &cs);
            const float o = oddc ? (val * cs + partner * sn)
                                 : (val * cs - partner * sn);
            dst[((size_t)(bidx * NH + h) * NS + s) * HD + d] = f2bf(o);
          }
        }
      }
    }
  }
}

// ---------------------------------------------------------------------------
// MFMA banded flash attention (fixed-reference softmax, R7; XCD swizzle,
// R10). R12 reverted R11's fast-path/bpermute variants: both were neutral-
// to-negative (mask VALU was already hidden by wave overlap; bpermute chain
// serialized the QK->PV transpose). Keep the simple masked loop + 16 shfl.
// ---------------------------------------------------------------------------
__global__ __launch_bounds__(256) void attn_mfma_kernel(
    const short* __restrict__ Qb, const short* __restrict__ Kb,
    const short* __restrict__ VT, short* __restrict__ CTXb,
    const int* __restrict__ layer_idx_p)
{
  const int lane = threadIdx.x & 63;
  const int wv = threadIdx.x >> 6;
  const int c = lane & 15;
  const int g = lane >> 4;

  // swizzle: xcd = id&7 owns bh in [xcd*3, xcd*3+3)
  const int id = blockIdx.x;
  const int xcd = id & 7;
  const int k = id >> 3;               // 0..95
  const int bh = xcd * 3 + (k >> 5);
  const int qt = k & 31;

  const int b = bh / NH;
  const int h = bh - b * NH;
  const int q0 = qt * 64 + wv * 16;
  const bool is_global = ((*layer_idx_p) % 3) == 0;
  const size_t base = (size_t)bh * NS * HD;

  const short* qrow = Qb + base + (size_t)(q0 + c) * HD + g * 8;
  const short8 qf0 = *(const short8*)(qrow);
  const short8 qf1 = *(const short8*)(qrow + 32);

  float4v O0 = {0.f, 0.f, 0.f, 0.f}, O1 = O0, O2 = O0, O3 = O0;
  float lacc = 0.0f;
  const int q = q0 + c;

  const int lo = is_global ? 0 : q0 - 128;
  const int hi = is_global ? (NS - 1) : q0 + 143;

  for (int kt = lo; kt <= hi; kt += 32) {
    if (kt + 31 < 0 || kt >= NS) continue;

    const int k1c = min(max(kt + c, 0), NS - 1);
    const int k2c = min(max(kt + 16 + c, 0), NS - 1);
    const short* kr1 = Kb + base + (size_t)k1c * HD + g * 8;
    const short* kr2 = Kb + base + (size_t)k2c * HD + g * 8;
    const short8 kf10 = *(const short8*)kr1;
    const short8 kf11 = *(const short8*)(kr1 + 32);
    const short8 kf20 = *(const short8*)kr2;
    const short8 kf21 = *(const short8*)(kr2 + 32);
    float4v st1 = {0.f, 0.f, 0.f, 0.f}, st2 = {0.f, 0.f, 0.f, 0.f};
    st1 = __builtin_amdgcn_mfma_f32_16x16x32_bf16(kf10, qf0, st1, 0, 0, 0);
    st1 = __builtin_amdgcn_mfma_f32_16x16x32_bf16(kf11, qf1, st1, 0, 0, 0);
    st2 = __builtin_amdgcn_mfma_f32_16x16x32_bf16(kf20, qf0, st2, 0, 0, 0);
    st2 = __builtin_amdgcn_mfma_f32_16x16x32_bf16(kf21, qf1, st2, 0, 0, 0);

    float p1[4], p2[4];
#pragma unroll
    for (int r = 0; r < 4; ++r) {
      const int key1 = kt + 4 * g + r;
      const int key2 = key1 + 16;
      const bool v1 = (key1 >= 0) & (key1 < NS) &
                      (is_global | ((key1 - q <= WIN) & (q - key1 <= WIN)));
      const bool v2 = (key2 >= 0) & (key2 < NS) &
                      (is_global | ((key2 - q <= WIN) & (q - key2 <= WIN)));
      p1[r] = __expf(v1 ? st1[r] * 0.125f : -1e30f);
      p2[r] = __expf(v2 ? st2[r] * 0.125f : -1e30f);
      lacc += p1[r] + p2[r];
    }

    const int srcA = (2 * (g & 1)) * 16 + c;
    const int srcB = srcA + 16;
    short8 pf;
#pragma unroll
    for (int r = 0; r < 4; ++r) {
      const float f1a = __shfl(p1[r], srcA);
      const float f1b = __shfl(p1[r], srcB);
      const float f2a = __shfl(p2[r], srcA);
      const float f2b = __shfl(p2[r], srcB);
      pf[r]     = f2bf((g < 2) ? f1a : f2a);
      pf[4 + r] = f2bf((g < 2) ? f1b : f2b);
    }

    const int ks = min(max(kt + 8 * g, 0), NS - 8);
    const short* vrow = VT + base + (size_t)c * NS + ks;
    const short8 vf0 = *(const short8*)(vrow);
    const short8 vf1 = *(const short8*)(vrow + 16 * NS);
    const short8 vf2 = *(const short8*)(vrow + 32 * NS);
    const short8 vf3 = *(const short8*)(vrow + 48 * NS);
    O0 = __builtin_amdgcn_mfma_f32_16x16x32_bf16(vf0, pf, O0, 0, 0, 0);
    O1 = __builtin_amdgcn_mfma_f32_16x16x32_bf16(vf1, pf, O1, 0, 0, 0);
    O2 = __builtin_amdgcn_mfma_f32_16x16x32_bf16(vf2, pf, O2, 0, 0, 0);
    O3 = __builtin_amdgcn_mfma_f32_16x16x32_bf16(vf3, pf, O3, 0, 0, 0);
  }

  // epilogue: one cross-quad reduction of l, then scale+store
  lacc += __shfl_xor(lacc, 16);
  lacc += __shfl_xor(lacc, 32);
  const float inv = 1.0f / lacc;
  short* crow = CTXb + ((size_t)(b * NS + q) * NH + h) * HD;
#pragma unroll
  for (int r = 0; r < 4; ++r) {
    const int d = 4 * g + r;
    crow[d]      = f2bf(O0[r] * inv);
    crow[d + 16] = f2bf(O1[r] * inv);
    crow[d + 32] = f2bf(O2[r] * inv);
    crow[d + 48] = f2bf(O3[r] * inv);
  }
}

// ---------------------------------------------------------------------------
extern "C" void kernel_launch(void* const* d_in, const int* in_sizes, int n_in,
                              void* d_out, int out_size, void* d_ws, size_t ws_size,
                              hipStream_t stream) {
  const float* x    = (const float*)d_in[0];
  const float* Wqkv = (const float*)d_in[1];
  const float* bqkv = (const float*)d_in[2];
  const float* Wout = (const float*)d_in[3];
  const float* bout = (const float*)d_in[4];
  const int* layer_idx = (const int*)d_in[5];

  short* xb    = (short*)d_ws;                         // [4096][768]
  short* Wqkvt = xb + (size_t)NB * NS * ND;            // [2304][768]
  short* Woutt = Wqkvt + (size_t)ND * N_QKV;           // [768][768]
  short* Qb    = Woutt + (size_t)ND * ND;              // [bh][s][64]
  short* Kb    = Qb + (size_t)QKN;
  short* VT    = Kb + (size_t)QKN;                     // [bh][64][s]
  short* CTXb  = VT + (size_t)QKN;                     // [4096][768]
  // total: 18087936 shorts = 36.2 MB

  // phase 0: all preps in one dispatch
  prep_kernel<<<5376, 256, 0, stream>>>(x, Wqkv, Wout, xb, Wqkvt, Woutt);

  // QKV GEMM + RoPE: M=4096, N=2304, K=768. 32 m-tiles x 36 n-tiles = 1152.
  mfma_gemm128_kernel<0><<<1152, 256, 0, stream>>>(
      xb, Wqkvt, bqkv, layer_idx, Qb, Kb, VT, nullptr, ND, N_QKV, 36, 4);

  attn_mfma_kernel<<<NB * NH * (NS / 64), 256, 0, stream>>>(Qb, Kb, VT, CTXb, layer_idx);

  // Out projection: M=4096, N=768, K=768. 32 m-tiles x 12 n-tiles = 384.
  mfma_gemm128_kernel<1><<<384, 256, 0, stream>>>(
      CTXb, Woutt, bout, layer_idx, nullptr, nullptr, nullptr, (float*)d_out, ND, ND, 12, 4);
}